// Round 4
// baseline (537.248 us; speedup 1.0000x reference)
//
#include <hip/hip_runtime.h>

#define Bn   64
#define Tn   128
#define NKn  200
#define En   64
#define Ln   40

__device__ __forceinline__ float sigm_f(float x){ return 1.0f/(1.0f+__expf(-x)); }
__device__ __forceinline__ float tanh_f(float x){ float e=__expf(2.0f*x); return 1.0f-2.0f/(e+1.0f); }
__device__ __forceinline__ float rdl(float v, int ln){
  return __uint_as_float(__builtin_amdgcn_readlane(__float_as_uint(v), (unsigned)ln));
}

// ---------------- both embedding gather-sums in one grid ----------------
__global__ __launch_bounds__(256) void embed_all(const int* __restrict__ sup,
                                                 const int* __restrict__ tgt,
                                                 const float* __restrict__ emb,
                                                 float* __restrict__ sup_enc,
                                                 float* __restrict__ tgt_enc){
  int tid = threadIdx.x;
  int gr  = blockIdx.x*16 + (tid>>4);
  int e4  = tid & 15;
  const int* tr; float* out;
  if (gr < 12800){ tr = sup + (size_t)gr*Ln;        out = sup_enc + (size_t)gr*64; }
  else           { int r2=gr-12800; tr = tgt + (size_t)r2*Ln; out = tgt_enc + (size_t)r2*64; }
  float4 acc = {0.f,0.f,0.f,0.f};
  #pragma unroll 4
  for (int t=0;t<Ln;t++){
    int tok = tr[t];
    float4 v = ((const float4*)emb)[(size_t)tok*16 + e4];
    acc.x+=v.x; acc.y+=v.y; acc.z+=v.z; acc.w+=v.w;
  }
  ((float4*)out)[e4] = acc;
}

// ---------------- both support GEMMs (gf + gb) in one grid ----------------
__global__ __launch_bounds__(256,2) void gemm_sup(const float* __restrict__ x,
                                                  const float* __restrict__ Wa, const float* __restrict__ Wb,
                                                  const float* __restrict__ ba1,const float* __restrict__ ba2,
                                                  const float* __restrict__ bb1,const float* __restrict__ bb2,
                                                  float* __restrict__ outa, float* __restrict__ outb){
  int tid=threadIdx.x, l=tid&63, w=tid>>6;
  int g = w*64+l;
  int blk = blockIdx.x;
  bool second = blk>=800;
  const float* W  = second? Wb : Wa;
  const float* b1 = second? bb1: ba1;
  const float* b2 = second? bb2: ba2;
  float* out      = second? outb: outa;
  int m0 = (second? blk-800 : blk)*16;
  float wr[64];
  const float4* W4=(const float4*)(W + (size_t)g*64);
  #pragma unroll
  for(int q=0;q<16;q++){ float4 v=W4[q]; wr[4*q]=v.x; wr[4*q+1]=v.y; wr[4*q+2]=v.z; wr[4*q+3]=v.w; }
  float bias=b1[g]+b2[g];
  float xr[16];
  #pragma unroll
  for(int r=0;r<16;r++) xr[r]=x[(size_t)(m0+r)*64+l];
  #pragma unroll
  for(int r=0;r<16;r++){
    float a0=bias,a1=0.f,a2=0.f,a3=0.f;
    #pragma unroll
    for(int q=0;q<16;q++){
      a0=fmaf(wr[4*q+0],rdl(xr[r],4*q+0),a0);
      a1=fmaf(wr[4*q+1],rdl(xr[r],4*q+1),a1);
      a2=fmaf(wr[4*q+2],rdl(xr[r],4*q+2),a2);
      a3=fmaf(wr[4*q+3],rdl(xr[r],4*q+3),a3);
    }
    out[(size_t)(m0+r)*256+g]=(a0+a1)+(a2+a3);
  }
}

// ---------------- BiLSTM: ONE WAVE per recurrence — no LDS, no barriers ----------------
// lane e holds all 4 gate rows (i,f,g,o) of Whh for element e; h lives lane-distributed;
// one readlane broadcast feeds 4 FMAs. 128 blocks x 64 threads = 1 wave/CU.
__global__ __launch_bounds__(64,1) void lstm_seq1w(const float* __restrict__ xg_f,
                                                   const float* __restrict__ xg_b,
                                                   const float* __restrict__ Whh_f,
                                                   const float* __restrict__ Whh_b,
                                                   float* __restrict__ hf,
                                                   float* __restrict__ hb){
  int e = threadIdx.x;
  int dir = blockIdx.x>>6, b = blockIdx.x&63;
  const float* xg = dir? xg_b : xg_f;
  const float* Whh= dir? Whh_b: Whh_f;
  float* out      = dir? hb : hf;
  float wi[64], wf[64], wg[64], wo[64];
  {
    const float4* Wi=(const float4*)(Whh + (size_t)(e)*64);
    const float4* Wf=(const float4*)(Whh + (size_t)(64+e)*64);
    const float4* Wg=(const float4*)(Whh + (size_t)(128+e)*64);
    const float4* Wo=(const float4*)(Whh + (size_t)(192+e)*64);
    #pragma unroll
    for(int q=0;q<16;q++){
      float4 a=Wi[q]; wi[4*q]=a.x; wi[4*q+1]=a.y; wi[4*q+2]=a.z; wi[4*q+3]=a.w;
      float4 c=Wf[q]; wf[4*q]=c.x; wf[4*q+1]=c.y; wf[4*q+2]=c.z; wf[4*q+3]=c.w;
      float4 d=Wg[q]; wg[4*q]=d.x; wg[4*q+1]=d.y; wg[4*q+2]=d.z; wg[4*q+3]=d.w;
      float4 f=Wo[q]; wo[4*q]=f.x; wo[4*q+1]=f.y; wo[4*q+2]=f.z; wo[4*q+3]=f.w;
    }
  }
  const int tstart = dir?(NKn-1):0, dt = dir?-1:1;
  const float* xr = xg + (size_t)b*NKn*256;
  float h=0.f, c=0.f;
  // depth-2 prefetch pipeline of the 4 xg gate values (no barriers -> stays in flight)
  float p0i,p0f,p0g,p0o, p1i,p1f,p1g,p1o;
  { const float* p=xr+(size_t)tstart*256;      p0i=p[e]; p0f=p[64+e]; p0g=p[128+e]; p0o=p[192+e]; }
  { const float* p=xr+(size_t)(tstart+dt)*256; p1i=p[e]; p1f=p[64+e]; p1g=p[128+e]; p1o=p[192+e]; }
  for(int s=0;s<NKn;s++){
    int t=tstart+s*dt;
    float ni=0.f,nf=0.f,ng=0.f,no=0.f;
    if (s+2<NKn){ const float* p=xr+(size_t)(t+2*dt)*256; ni=p[e]; nf=p[64+e]; ng=p[128+e]; no=p[192+e]; }
    float zi=p0i, zf=p0f, zg=p0g, zo=p0o;
    #pragma unroll
    for(int k=0;k<64;k++){
      float hs=rdl(h,k);
      zi=fmaf(wi[k],hs,zi);
      zf=fmaf(wf[k],hs,zf);
      zg=fmaf(wg[k],hs,zg);
      zo=fmaf(wo[k],hs,zo);
    }
    c = sigm_f(zf)*c + sigm_f(zi)*tanh_f(zg);
    h = sigm_f(zo)*tanh_f(c);
    out[((size_t)b*NKn+t)*64+e]=h;
    p0i=p1i; p0f=p1f; p0g=p1g; p0o=p1o;
    p1i=ni;  p1f=nf;  p1g=ng;  p1o=no;
  }
}

// ---------------- zx GEMM (blocks 0..511) + combine/norms (blocks 512..1311) --------------
__global__ __launch_bounds__(256,2) void gemmz_combine(const float* __restrict__ tgt_enc,
                                                       const float* __restrict__ W,
                                                       const float* __restrict__ b1,
                                                       const float* __restrict__ b2,
                                                       float* __restrict__ zx,
                                                       const float* __restrict__ hf,
                                                       const float* __restrict__ hb,
                                                       const float* __restrict__ sup_enc,
                                                       float* __restrict__ semb,
                                                       float* __restrict__ sn){
  int tid=threadIdx.x, l=tid&63, w=tid>>6;
  int blk=blockIdx.x;
  if (blk < 512){
    int g=w*64+l, m0=blk*16;
    float wr[64];
    const float4* W4=(const float4*)(W + (size_t)g*64);
    #pragma unroll
    for(int q=0;q<16;q++){ float4 v=W4[q]; wr[4*q]=v.x; wr[4*q+1]=v.y; wr[4*q+2]=v.z; wr[4*q+3]=v.w; }
    float bias=b1[g]+b2[g];
    float xr[16];
    #pragma unroll
    for(int r=0;r<16;r++) xr[r]=tgt_enc[(size_t)(m0+r)*64+l];
    #pragma unroll
    for(int r=0;r<16;r++){
      float a0=bias,a1=0.f,a2=0.f,a3=0.f;
      #pragma unroll
      for(int q=0;q<16;q++){
        a0=fmaf(wr[4*q+0],rdl(xr[r],4*q+0),a0);
        a1=fmaf(wr[4*q+1],rdl(xr[r],4*q+1),a1);
        a2=fmaf(wr[4*q+2],rdl(xr[r],4*q+2),a2);
        a3=fmaf(wr[4*q+3],rdl(xr[r],4*q+3),a3);
      }
      zx[(size_t)(m0+r)*256+g]=(a0+a1)+(a2+a3);
    }
  } else {
    int m0=(blk-512)*16;
    #pragma unroll
    for(int q=0;q<4;q++){
      size_t m=(size_t)m0 + w*4 + q;
      float v = hf[m*64+l] + hb[m*64+l] + sup_enc[m*64+l];
      semb[m*64+l]=v;
      float s=v*v;
      #pragma unroll
      for (int o=32;o>0;o>>=1) s += __shfl_xor(s,o,64);
      if (l==0) sn[m]=sqrtf(s);
    }
  }
}

// ---------------- fused LSTM-cell + attention: cell & scores GEMVs share one broadcast
// stream (1 rdl -> 2 fma); outputs hu = h_next + r directly ----------------
__global__ __launch_bounds__(256,2) void fused_cell_attn(const float* __restrict__ hu_in,
                                                         const float* __restrict__ zx,
                                                         const float* __restrict__ Whh,
                                                         const float* __restrict__ x,
                                                         float* __restrict__ c_io,
                                                         const float* __restrict__ semb,
                                                         float* __restrict__ hu_out,
                                                         int zero){
  int tid=threadIdx.x, l=tid&63, w=tid>>6;
  int b=blockIdx.x>>3, t0=(blockIdx.x&7)*16;
  int m0=b*Tn+t0;
  int g=tid;                      // gate index AND support-row index j
  __shared__ float sbuf[5120];    // z (16x256) / att (200x20), + h_next (16x64) @4096
  __shared__ float wredA[64], wredB[64];
  bool valid = g<NKn;
  const float* sbase = semb + (size_t)b*NKn*64;
  float wr[64];
  {
    const float4* W4=(const float4*)(Whh+(size_t)g*64);
    #pragma unroll
    for(int q=0;q<16;q++){ float4 v=W4[q]; wr[4*q]=v.x; wr[4*q+1]=v.y; wr[4*q+2]=v.z; wr[4*q+3]=v.w; }
  }
  float s4f[64];
  if(valid){
    const float4* sp=(const float4*)(sbase+(size_t)g*64);
    #pragma unroll
    for(int q=0;q<16;q++){ float4 v=sp[q]; s4f[4*q]=v.x; s4f[4*q+1]=v.y; s4f[4*q+2]=v.z; s4f[4*q+3]=v.w; }
  } else {
    #pragma unroll
    for(int q=0;q<64;q++) s4f[q]=0.f;
  }
  float hur[16];
  #pragma unroll
  for(int r=0;r<16;r++) hur[r] = zero? 0.f : hu_in[(size_t)(m0+r)*64+l];
  // ---- fused cell + scores GEMV: one broadcast stream ----
  float scr[16];
  #pragma unroll
  for(int r=0;r<16;r++){
    float z0=zx[(size_t)(m0+r)*256+g], z1=0.f, sc0=0.f, sc1=0.f;
    if(!zero){
      #pragma unroll
      for(int k=0;k<64;k+=2){
        float h0=rdl(hur[r],k), h1=rdl(hur[r],k+1);
        z0 =fmaf(wr[k]  ,h0,z0 ); sc0=fmaf(s4f[k]  ,h0,sc0);
        z1 =fmaf(wr[k+1],h1,z1 ); sc1=fmaf(s4f[k+1],h1,sc1);
      }
    }
    sbuf[r*256+tid]=z0+z1;
    scr[r]=sc0+sc1;
  }
  __syncthreads();
  // ---- gates -> h_next (to LDS @4096) ----
  #pragma unroll
  for(int q=0;q<4;q++){
    int r=q*4+w; size_t m=(size_t)(m0+r);
    float zi=sbuf[r*256+l], zf=sbuf[r*256+64+l], zg=sbuf[r*256+128+l], zo=sbuf[r*256+192+l];
    float cp = zero? 0.f : c_io[m*64+l];
    float c=sigm_f(zf)*cp+sigm_f(zi)*tanh_f(zg);
    c_io[m*64+l]=c;
    sbuf[4096 + r*64 + l]=sigm_f(zo)*tanh_f(c)+x[m*64+l];
  }
  // ---- softmax over j for each of 16 targets ----
  float mx[16];
  #pragma unroll
  for(int t=0;t<16;t++){
    float m = valid ? scr[t] : -1e30f;
    #pragma unroll
    for(int o=32;o>0;o>>=1) m=fmaxf(m,__shfl_xor(m,o,64));
    mx[t]=m;
  }
  if(l==0){
    #pragma unroll
    for(int t=0;t<16;t++) wredA[t*4+w]=mx[t];
  }
  __syncthreads();                   // all z-reads done before att overwrites sbuf
  float ex[16];
  #pragma unroll
  for(int t=0;t<16;t++){
    const float4 m4=*(const float4*)&wredA[t*4];
    float gm=fmaxf(fmaxf(m4.x,m4.y),fmaxf(m4.z,m4.w));
    float e=valid?__expf(scr[t]-gm):0.f;
    ex[t]=e;
    float s=e;
    #pragma unroll
    for(int o=32;o>0;o>>=1) s+=__shfl_xor(s,o,64);
    mx[t]=s;
  }
  if(l==0){
    #pragma unroll
    for(int t=0;t<16;t++) wredB[t*4+w]=mx[t];
  }
  __syncthreads();
  #pragma unroll
  for(int t=0;t<16;t++){
    const float4 s4v=*(const float4*)&wredB[t*4];
    float tot=(s4v.x+s4v.y)+(s4v.z+s4v.w);
    ex[t]*=1.0f/tot;                 // att
  }
  if(valid){
    #pragma unroll
    for(int cg=0;cg<4;cg++)
      *(float4*)&sbuf[g*20+4*cg]=make_float4(ex[4*cg+0],ex[4*cg+1],ex[4*cg+2],ex[4*cg+3]);
  }
  __syncthreads();
  // ---- r-phase: wave w owns targets w*4..w*4+3; lane = e ----
  float4 areg[4];
  #pragma unroll
  for(int c2=0;c2<4;c2++){
    int jj=c2*64+l;
    areg[c2]=(jj<NKn)? *(const float4*)&sbuf[jj*20+w*4] : make_float4(0.f,0.f,0.f,0.f);
  }
  float r0=0.f,r1=0.f,r2=0.f,r3=0.f;
  #pragma unroll
  for(int c2=0;c2<4;c2++){
    const int lim=(c2<3)?64:(NKn-192);
    #pragma unroll 16
    for(int jl=0;jl<lim;jl++){
      float sv=sbase[(size_t)(c2*64+jl)*64+l];   // L2-resident global read
      r0=fmaf(rdl(areg[c2].x,jl),sv,r0);
      r1=fmaf(rdl(areg[c2].y,jl),sv,r1);
      r2=fmaf(rdl(areg[c2].z,jl),sv,r2);
      r3=fmaf(rdl(areg[c2].w,jl),sv,r3);
    }
  }
  {
    int rb=w*4;
    size_t m=(size_t)(m0+rb);
    hu_out[(m+0)*64+l]=r0 + sbuf[4096+(rb+0)*64+l];
    hu_out[(m+1)*64+l]=r1 + sbuf[4096+(rb+1)*64+l];
    hu_out[(m+2)*64+l]=r2 + sbuf[4096+(rb+2)*64+l];
    hu_out[(m+3)*64+l]=r3 + sbuf[4096+(rb+3)*64+l];
  }
}

// ---------------- fused final cell + cosine-sim softmax -> d_out ----------------
__global__ __launch_bounds__(256,2) void fused_cell_final(const float* __restrict__ hu_in,
                                                          const float* __restrict__ zx,
                                                          const float* __restrict__ Whh,
                                                          const float* __restrict__ x,
                                                          const float* __restrict__ c_in,
                                                          const float* __restrict__ semb,
                                                          const float* __restrict__ sn,
                                                          float* __restrict__ out){
  int tid=threadIdx.x, l=tid&63, w=tid>>6;
  int b=blockIdx.x>>3, t0=(blockIdx.x&7)*16;
  int m0=b*Tn+t0;
  int g=tid;
  __shared__ float sbuf[5120];     // z (16x256) + h_fin (16x64) @4096
  __shared__ float wredA[64], wredB[64];
  float wr[64];
  {
    const float4* W4=(const float4*)(Whh+(size_t)g*64);
    #pragma unroll
    for(int q=0;q<16;q++){ float4 v=W4[q]; wr[4*q]=v.x; wr[4*q+1]=v.y; wr[4*q+2]=v.z; wr[4*q+3]=v.w; }
  }
  float hur[16];
  #pragma unroll
  for(int r=0;r<16;r++) hur[r]=hu_in[(size_t)(m0+r)*64+l];
  #pragma unroll
  for(int r=0;r<16;r++){
    float a0=zx[(size_t)(m0+r)*256+g],a1=0.f;
    #pragma unroll
    for(int k=0;k<64;k+=2){
      float h0=rdl(hur[r],k), h1=rdl(hur[r],k+1);
      a0=fmaf(wr[k]  ,h0,a0);
      a1=fmaf(wr[k+1],h1,a1);
    }
    sbuf[r*256+tid]=a0+a1;
  }
  __syncthreads();
  #pragma unroll
  for(int q=0;q<4;q++){
    int r=q*4+w; size_t m=(size_t)(m0+r);
    float zi=sbuf[r*256+l], zf=sbuf[r*256+64+l], zg=sbuf[r*256+128+l], zo=sbuf[r*256+192+l];
    float c=sigm_f(zf)*c_in[m*64+l]+sigm_f(zi)*tanh_f(zg);
    sbuf[4096 + r*64 + l]=sigm_f(zo)*tanh_f(c)+x[m*64+l];   // h_fin
  }
  __syncthreads();
  float hreg[16], tnorm[16];
  #pragma unroll
  for(int r=0;r<16;r++) hreg[r]=sbuf[4096+r*64+l];
  #pragma unroll
  for(int t=0;t<16;t++){
    float s=hreg[t]*hreg[t];
    #pragma unroll
    for(int o=32;o>0;o>>=1) s+=__shfl_xor(s,o,64);
    tnorm[t]=sqrtf(s);
  }
  bool valid=g<NKn;
  float snj = valid ? sn[(size_t)b*NKn+g] : 1.f;
  float s4f[64];
  if(valid){
    const float4* sp=(const float4*)(semb+((size_t)b*NKn+g)*64);
    #pragma unroll
    for(int q=0;q<16;q++){ float4 v=sp[q]; s4f[4*q]=v.x; s4f[4*q+1]=v.y; s4f[4*q+2]=v.z; s4f[4*q+3]=v.w; }
  } else {
    #pragma unroll
    for(int q=0;q<64;q++) s4f[q]=0.f;
  }
  float scr[16];
  #pragma unroll
  for(int t=0;t<16;t++){
    float a0=0.f,a1=0.f;
    #pragma unroll
    for(int k=0;k<64;k+=2){
      float h0=rdl(hreg[t],k), h1=rdl(hreg[t],k+1);
      a0=fmaf(s4f[k]  ,h0,a0);
      a1=fmaf(s4f[k+1],h1,a1);
    }
    scr[t]=(a0+a1) / fmaxf(tnorm[t]*snj,1e-8f);
  }
  float mx[16];
  #pragma unroll
  for(int t=0;t<16;t++){
    float m = valid ? scr[t] : -1e30f;
    #pragma unroll
    for(int o=32;o>0;o>>=1) m=fmaxf(m,__shfl_xor(m,o,64));
    mx[t]=m;
  }
  if(l==0){
    #pragma unroll
    for(int t=0;t<16;t++) wredA[t*4+w]=mx[t];
  }
  __syncthreads();
  float ex[16];
  #pragma unroll
  for(int t=0;t<16;t++){
    const float4 m4=*(const float4*)&wredA[t*4];
    float gm=fmaxf(fmaxf(m4.x,m4.y),fmaxf(m4.z,m4.w));
    float e=valid?__expf(scr[t]-gm):0.f;
    ex[t]=e;
    float s=e;
    #pragma unroll
    for(int o=32;o>0;o>>=1) s+=__shfl_xor(s,o,64);
    mx[t]=s;
  }
  if(l==0){
    #pragma unroll
    for(int t=0;t<16;t++) wredB[t*4+w]=mx[t];
  }
  __syncthreads();
  #pragma unroll
  for(int t=0;t<16;t++){
    const float4 s4v=*(const float4*)&wredB[t*4];
    float tot=(s4v.x+s4v.y)+(s4v.z+s4v.w);
    if(valid) out[((size_t)(m0+t))*NKn + g]=ex[t]*(1.0f/tot);
  }
}

extern "C" void kernel_launch(void* const* d_in, const int* in_sizes, int n_in,
                              void* d_out, int out_size, void* d_ws, size_t ws_size,
                              hipStream_t stream) {
  (void)in_sizes; (void)n_in; (void)out_size; (void)ws_size;
  const int*   sup_toks = (const int*)d_in[0];
  const int*   tgt_toks = (const int*)d_in[1];
  const float* emb      = (const float*)d_in[2];
  const float* f_Wih    = (const float*)d_in[3];
  const float* f_Whh    = (const float*)d_in[4];
  const float* f_bih    = (const float*)d_in[5];
  const float* f_bhh    = (const float*)d_in[6];
  const float* gf_Wih   = (const float*)d_in[7];
  const float* gf_Whh   = (const float*)d_in[8];
  const float* gf_bih   = (const float*)d_in[9];
  const float* gf_bhh   = (const float*)d_in[10];
  const float* gb_Wih   = (const float*)d_in[11];
  const float* gb_Whh   = (const float*)d_in[12];
  const float* gb_bih   = (const float*)d_in[13];
  const float* gb_bhh   = (const float*)d_in[14];

  float* ws = (float*)d_ws;
  float* sup_enc = ws;                         // 819200
  float* tgt_enc = sup_enc + 819200;           // 524288
  float* bufA    = tgt_enc + 524288;           // 3276800 : xg_f, later zx
  float* bufB    = bufA    + 3276800;          // 3276800 : xg_b, later huA/huB/c
  float* semb    = bufB    + 3276800;          // 819200  : hf, then sup_emb
  float* hb      = semb    + 819200;           // 819200
  float* sn      = hb      + 819200;           // 12800

  float* xg_f = bufA;
  float* xg_b = bufB;

  embed_all<<<1312,256,0,stream>>>(sup_toks, tgt_toks, emb, sup_enc, tgt_enc);
  gemm_sup<<<1600,256,0,stream>>>(sup_enc, gf_Wih, gb_Wih,
                                  gf_bih, gf_bhh, gb_bih, gb_bhh, xg_f, xg_b);
  lstm_seq1w<<<128,64,0,stream>>>(xg_f, xg_b, gf_Whh, gb_Whh, semb /*hf*/, hb);

  float* zx   = bufA;                  // xg_f dead after lstm
  float* huA  = bufB;                  // xg_b dead after lstm
  float* huB  = huA + 524288;
  float* cbuf = huB + 524288;

  gemmz_combine<<<1312,256,0,stream>>>(tgt_enc, f_Wih, f_bih, f_bhh, zx,
                                       semb, hb, sup_enc, semb, sn);

  // K=5: hu ping-pong; k=0 zero-init; k=4 fused with final softmax
  fused_cell_attn<<<512,256,0,stream>>>(huA, zx, f_Whh, tgt_enc, cbuf, semb, huA, 1);
  fused_cell_attn<<<512,256,0,stream>>>(huA, zx, f_Whh, tgt_enc, cbuf, semb, huB, 0);
  fused_cell_attn<<<512,256,0,stream>>>(huB, zx, f_Whh, tgt_enc, cbuf, semb, huA, 0);
  fused_cell_attn<<<512,256,0,stream>>>(huA, zx, f_Whh, tgt_enc, cbuf, semb, huB, 0);
  fused_cell_final<<<512,256,0,stream>>>(huB, zx, f_Whh, tgt_enc, cbuf, semb, sn, (float*)d_out);
}

// Round 5
// 508.681 us; speedup vs baseline: 1.0562x; 1.0562x over previous
//
#include <hip/hip_runtime.h>

#define Bn   64
#define Tn   128
#define NKn  200
#define En   64
#define Ln   40

__device__ __forceinline__ float sigm_f(float x){ return 1.0f/(1.0f+__expf(-x)); }
__device__ __forceinline__ float tanh_f(float x){ float e=__expf(2.0f*x); return 1.0f-2.0f/(e+1.0f); }
__device__ __forceinline__ float rdl(float v, int ln){
  return __uint_as_float(__builtin_amdgcn_readlane(__float_as_uint(v), (unsigned)ln));
}

// ---------------- both embedding gather-sums in one grid ----------------
__global__ __launch_bounds__(256) void embed_all(const int* __restrict__ sup,
                                                 const int* __restrict__ tgt,
                                                 const float* __restrict__ emb,
                                                 float* __restrict__ sup_enc,
                                                 float* __restrict__ tgt_enc){
  int tid = threadIdx.x;
  int gr  = blockIdx.x*16 + (tid>>4);
  int e4  = tid & 15;
  const int* tr; float* out;
  if (gr < 12800){ tr = sup + (size_t)gr*Ln;        out = sup_enc + (size_t)gr*64; }
  else           { int r2=gr-12800; tr = tgt + (size_t)r2*Ln; out = tgt_enc + (size_t)r2*64; }
  float4 acc = {0.f,0.f,0.f,0.f};
  #pragma unroll 4
  for (int t=0;t<Ln;t++){
    int tok = tr[t];
    float4 v = ((const float4*)emb)[(size_t)tok*16 + e4];
    acc.x+=v.x; acc.y+=v.y; acc.z+=v.z; acc.w+=v.w;
  }
  ((float4*)out)[e4] = acc;
}

// ---------------- both support GEMMs (gf + gb) in one grid ----------------
__global__ __launch_bounds__(256,2) void gemm_sup(const float* __restrict__ x,
                                                  const float* __restrict__ Wa, const float* __restrict__ Wb,
                                                  const float* __restrict__ ba1,const float* __restrict__ ba2,
                                                  const float* __restrict__ bb1,const float* __restrict__ bb2,
                                                  float* __restrict__ outa, float* __restrict__ outb){
  int tid=threadIdx.x, l=tid&63, w=tid>>6;
  int g = w*64+l;
  int blk = blockIdx.x;
  bool second = blk>=800;
  const float* W  = second? Wb : Wa;
  const float* b1 = second? bb1: ba1;
  const float* b2 = second? bb2: ba2;
  float* out      = second? outb: outa;
  int m0 = (second? blk-800 : blk)*16;
  float wr[64];
  const float4* W4=(const float4*)(W + (size_t)g*64);
  #pragma unroll
  for(int q=0;q<16;q++){ float4 v=W4[q]; wr[4*q]=v.x; wr[4*q+1]=v.y; wr[4*q+2]=v.z; wr[4*q+3]=v.w; }
  float bias=b1[g]+b2[g];
  float xr[16];
  #pragma unroll
  for(int r=0;r<16;r++) xr[r]=x[(size_t)(m0+r)*64+l];
  #pragma unroll
  for(int r=0;r<16;r++){
    float a0=bias,a1=0.f,a2=0.f,a3=0.f;
    #pragma unroll
    for(int q=0;q<16;q++){
      a0=fmaf(wr[4*q+0],rdl(xr[r],4*q+0),a0);
      a1=fmaf(wr[4*q+1],rdl(xr[r],4*q+1),a1);
      a2=fmaf(wr[4*q+2],rdl(xr[r],4*q+2),a2);
      a3=fmaf(wr[4*q+3],rdl(xr[r],4*q+3),a3);
    }
    out[(size_t)(m0+r)*256+g]=(a0+a1)+(a2+a3);
  }
}

// ---------------- BiLSTM: 2 chains (same dir, shared weights) per block ----------------
// 64 blocks x 256 thr. Wave w, lane l -> gate g=w*64+l holds wr[64] (shared by both
// chains). Two independent rdl->fma streams interleave to hide the readlane hazard.
// z crosses waves via parity-double-buffered LDS -> ONE barrier/step.
__global__ __launch_bounds__(256,1) void lstm_seq2(const float* __restrict__ xg_f,
                                                   const float* __restrict__ xg_b,
                                                   const float* __restrict__ Whh_f,
                                                   const float* __restrict__ Whh_b,
                                                   float* __restrict__ hf,
                                                   float* __restrict__ hb){
  int tid=threadIdx.x, l=tid&63, w=tid>>6;
  int dir = blockIdx.x>>5;         // 0..1
  int pair= blockIdx.x&31;         // 0..31
  int b0 = pair*2, b1 = pair*2+1;
  const float* xg = dir? xg_b : xg_f;
  const float* Whh= dir? Whh_b: Whh_f;
  float* out      = dir? hb : hf;
  int g = w*64+l;
  float wr[64];
  {
    const float4* W4=(const float4*)(Whh+(size_t)g*64);
    #pragma unroll
    for(int q=0;q<16;q++){ float4 v=W4[q]; wr[4*q]=v.x; wr[4*q+1]=v.y; wr[4*q+2]=v.z; wr[4*q+3]=v.w; }
  }
  __shared__ float z_s[2][2][256];       // [parity][chain][gate]
  float h0=0.f,c0=0.f,h1=0.f,c1=0.f;
  const int tstart = dir?(NKn-1):0, dt = dir?-1:1;
  const float* x0 = xg + (size_t)b0*NKn*256 + g;
  const float* x1 = xg + (size_t)b1*NKn*256 + g;
  for(int s=0;s<NKn;s++){
    int t=tstart+s*dt;
    float xv0 = x0[(size_t)t*256];       // issued early; consumed ~500 cyc later
    float xv1 = x1[(size_t)t*256];
    float a00=0.f,a01=0.f,a10=0.f,a11=0.f;
    #pragma unroll
    for(int k=0;k<64;k+=2){
      float h0a=rdl(h0,k), h0b=rdl(h0,k+1);
      float h1a=rdl(h1,k), h1b=rdl(h1,k+1);
      a00=fmaf(wr[k]  ,h0a,a00);
      a10=fmaf(wr[k]  ,h1a,a10);
      a01=fmaf(wr[k+1],h0b,a01);
      a11=fmaf(wr[k+1],h1b,a11);
    }
    int p=s&1;
    z_s[p][0][tid]=xv0+a00+a01;
    z_s[p][1][tid]=xv1+a10+a11;
    __syncthreads();                     // single barrier; parity buffer protects next write
    {
      float zi=z_s[p][0][l], zf=z_s[p][0][64+l], zg2=z_s[p][0][128+l], zo=z_s[p][0][192+l];
      c0 = sigm_f(zf)*c0 + sigm_f(zi)*tanh_f(zg2);
      h0 = sigm_f(zo)*tanh_f(c0);
    }
    {
      float zi=z_s[p][1][l], zf=z_s[p][1][64+l], zg2=z_s[p][1][128+l], zo=z_s[p][1][192+l];
      c1 = sigm_f(zf)*c1 + sigm_f(zi)*tanh_f(zg2);
      h1 = sigm_f(zo)*tanh_f(c1);
    }
    if(w==0){
      out[((size_t)b0*NKn+t)*64+l]=h0;
      out[((size_t)b1*NKn+t)*64+l]=h1;
    }
  }
}

// ---------------- zx GEMM (blocks 0..511) + combine/norms (blocks 512..1311) --------------
__global__ __launch_bounds__(256,2) void gemmz_combine(const float* __restrict__ tgt_enc,
                                                       const float* __restrict__ W,
                                                       const float* __restrict__ b1,
                                                       const float* __restrict__ b2,
                                                       float* __restrict__ zx,
                                                       const float* __restrict__ hf,
                                                       const float* __restrict__ hb,
                                                       const float* __restrict__ sup_enc,
                                                       float* __restrict__ semb,
                                                       float* __restrict__ sn){
  int tid=threadIdx.x, l=tid&63, w=tid>>6;
  int blk=blockIdx.x;
  if (blk < 512){
    int g=w*64+l, m0=blk*16;
    float wr[64];
    const float4* W4=(const float4*)(W + (size_t)g*64);
    #pragma unroll
    for(int q=0;q<16;q++){ float4 v=W4[q]; wr[4*q]=v.x; wr[4*q+1]=v.y; wr[4*q+2]=v.z; wr[4*q+3]=v.w; }
    float bias=b1[g]+b2[g];
    float xr[16];
    #pragma unroll
    for(int r=0;r<16;r++) xr[r]=tgt_enc[(size_t)(m0+r)*64+l];
    #pragma unroll
    for(int r=0;r<16;r++){
      float a0=bias,a1=0.f,a2=0.f,a3=0.f;
      #pragma unroll
      for(int q=0;q<16;q++){
        a0=fmaf(wr[4*q+0],rdl(xr[r],4*q+0),a0);
        a1=fmaf(wr[4*q+1],rdl(xr[r],4*q+1),a1);
        a2=fmaf(wr[4*q+2],rdl(xr[r],4*q+2),a2);
        a3=fmaf(wr[4*q+3],rdl(xr[r],4*q+3),a3);
      }
      zx[(size_t)(m0+r)*256+g]=(a0+a1)+(a2+a3);
    }
  } else {
    int m0=(blk-512)*16;
    #pragma unroll
    for(int q=0;q<4;q++){
      size_t m=(size_t)m0 + w*4 + q;
      float v = hf[m*64+l] + hb[m*64+l] + sup_enc[m*64+l];
      semb[m*64+l]=v;
      float s=v*v;
      #pragma unroll
      for (int o=32;o>0;o>>=1) s += __shfl_xor(s,o,64);
      if (l==0) sn[m]=sqrtf(s);
    }
  }
}

// ---------------- fused LSTM-cell + attention: cell & scores GEMVs share one broadcast
// stream (1 rdl -> 2 fma); outputs hu = h_next + r directly ----------------
__global__ __launch_bounds__(256,2) void fused_cell_attn(const float* __restrict__ hu_in,
                                                         const float* __restrict__ zx,
                                                         const float* __restrict__ Whh,
                                                         const float* __restrict__ x,
                                                         float* __restrict__ c_io,
                                                         const float* __restrict__ semb,
                                                         float* __restrict__ hu_out,
                                                         int zero){
  int tid=threadIdx.x, l=tid&63, w=tid>>6;
  int b=blockIdx.x>>3, t0=(blockIdx.x&7)*16;
  int m0=b*Tn+t0;
  int g=tid;                      // gate index AND support-row index j
  __shared__ float sbuf[5120];    // z (16x256) / att (200x20), + h_next (16x64) @4096
  __shared__ float wredA[64], wredB[64];
  bool valid = g<NKn;
  const float* sbase = semb + (size_t)b*NKn*64;
  float wr[64];
  {
    const float4* W4=(const float4*)(Whh+(size_t)g*64);
    #pragma unroll
    for(int q=0;q<16;q++){ float4 v=W4[q]; wr[4*q]=v.x; wr[4*q+1]=v.y; wr[4*q+2]=v.z; wr[4*q+3]=v.w; }
  }
  float s4f[64];
  if(valid){
    const float4* sp=(const float4*)(sbase+(size_t)g*64);
    #pragma unroll
    for(int q=0;q<16;q++){ float4 v=sp[q]; s4f[4*q]=v.x; s4f[4*q+1]=v.y; s4f[4*q+2]=v.z; s4f[4*q+3]=v.w; }
  } else {
    #pragma unroll
    for(int q=0;q<64;q++) s4f[q]=0.f;
  }
  float hur[16];
  #pragma unroll
  for(int r=0;r<16;r++) hur[r] = zero? 0.f : hu_in[(size_t)(m0+r)*64+l];
  // ---- fused cell + scores GEMV: one broadcast stream ----
  float scr[16];
  #pragma unroll
  for(int r=0;r<16;r++){
    float z0=zx[(size_t)(m0+r)*256+g], z1=0.f, sc0=0.f, sc1=0.f;
    if(!zero){
      #pragma unroll
      for(int k=0;k<64;k+=2){
        float h0=rdl(hur[r],k), h1=rdl(hur[r],k+1);
        z0 =fmaf(wr[k]  ,h0,z0 ); sc0=fmaf(s4f[k]  ,h0,sc0);
        z1 =fmaf(wr[k+1],h1,z1 ); sc1=fmaf(s4f[k+1],h1,sc1);
      }
    }
    sbuf[r*256+tid]=z0+z1;
    scr[r]=sc0+sc1;
  }
  __syncthreads();
  // ---- gates -> h_next (to LDS @4096) ----
  #pragma unroll
  for(int q=0;q<4;q++){
    int r=q*4+w; size_t m=(size_t)(m0+r);
    float zi=sbuf[r*256+l], zf=sbuf[r*256+64+l], zg=sbuf[r*256+128+l], zo=sbuf[r*256+192+l];
    float cp = zero? 0.f : c_io[m*64+l];
    float c=sigm_f(zf)*cp+sigm_f(zi)*tanh_f(zg);
    c_io[m*64+l]=c;
    sbuf[4096 + r*64 + l]=sigm_f(zo)*tanh_f(c)+x[m*64+l];
  }
  // ---- softmax over j for each of 16 targets ----
  float mx[16];
  #pragma unroll
  for(int t=0;t<16;t++){
    float m = valid ? scr[t] : -1e30f;
    #pragma unroll
    for(int o=32;o>0;o>>=1) m=fmaxf(m,__shfl_xor(m,o,64));
    mx[t]=m;
  }
  if(l==0){
    #pragma unroll
    for(int t=0;t<16;t++) wredA[t*4+w]=mx[t];
  }
  __syncthreads();                   // all z-reads done before att overwrites sbuf
  float ex[16];
  #pragma unroll
  for(int t=0;t<16;t++){
    const float4 m4=*(const float4*)&wredA[t*4];
    float gm=fmaxf(fmaxf(m4.x,m4.y),fmaxf(m4.z,m4.w));
    float e=valid?__expf(scr[t]-gm):0.f;
    ex[t]=e;
    float s=e;
    #pragma unroll
    for(int o=32;o>0;o>>=1) s+=__shfl_xor(s,o,64);
    mx[t]=s;
  }
  if(l==0){
    #pragma unroll
    for(int t=0;t<16;t++) wredB[t*4+w]=mx[t];
  }
  __syncthreads();
  #pragma unroll
  for(int t=0;t<16;t++){
    const float4 s4v=*(const float4*)&wredB[t*4];
    float tot=(s4v.x+s4v.y)+(s4v.z+s4v.w);
    ex[t]*=1.0f/tot;                 // att
  }
  if(valid){
    #pragma unroll
    for(int cg=0;cg<4;cg++)
      *(float4*)&sbuf[g*20+4*cg]=make_float4(ex[4*cg+0],ex[4*cg+1],ex[4*cg+2],ex[4*cg+3]);
  }
  __syncthreads();
  // ---- r-phase: wave w owns targets w*4..w*4+3; lane = e ----
  float4 areg[4];
  #pragma unroll
  for(int c2=0;c2<4;c2++){
    int jj=c2*64+l;
    areg[c2]=(jj<NKn)? *(const float4*)&sbuf[jj*20+w*4] : make_float4(0.f,0.f,0.f,0.f);
  }
  float r0=0.f,r1=0.f,r2=0.f,r3=0.f;
  #pragma unroll
  for(int c2=0;c2<4;c2++){
    const int lim=(c2<3)?64:(NKn-192);
    #pragma unroll 16
    for(int jl=0;jl<lim;jl++){
      float sv=sbase[(size_t)(c2*64+jl)*64+l];   // L2-resident global read
      r0=fmaf(rdl(areg[c2].x,jl),sv,r0);
      r1=fmaf(rdl(areg[c2].y,jl),sv,r1);
      r2=fmaf(rdl(areg[c2].z,jl),sv,r2);
      r3=fmaf(rdl(areg[c2].w,jl),sv,r3);
    }
  }
  {
    int rb=w*4;
    size_t m=(size_t)(m0+rb);
    hu_out[(m+0)*64+l]=r0 + sbuf[4096+(rb+0)*64+l];
    hu_out[(m+1)*64+l]=r1 + sbuf[4096+(rb+1)*64+l];
    hu_out[(m+2)*64+l]=r2 + sbuf[4096+(rb+2)*64+l];
    hu_out[(m+3)*64+l]=r3 + sbuf[4096+(rb+3)*64+l];
  }
}

// ---------------- fused final cell + cosine-sim softmax -> d_out ----------------
__global__ __launch_bounds__(256,2) void fused_cell_final(const float* __restrict__ hu_in,
                                                          const float* __restrict__ zx,
                                                          const float* __restrict__ Whh,
                                                          const float* __restrict__ x,
                                                          const float* __restrict__ c_in,
                                                          const float* __restrict__ semb,
                                                          const float* __restrict__ sn,
                                                          float* __restrict__ out){
  int tid=threadIdx.x, l=tid&63, w=tid>>6;
  int b=blockIdx.x>>3, t0=(blockIdx.x&7)*16;
  int m0=b*Tn+t0;
  int g=tid;
  __shared__ float sbuf[5120];     // z (16x256) + h_fin (16x64) @4096
  __shared__ float wredA[64], wredB[64];
  float wr[64];
  {
    const float4* W4=(const float4*)(Whh+(size_t)g*64);
    #pragma unroll
    for(int q=0;q<16;q++){ float4 v=W4[q]; wr[4*q]=v.x; wr[4*q+1]=v.y; wr[4*q+2]=v.z; wr[4*q+3]=v.w; }
  }
  float hur[16];
  #pragma unroll
  for(int r=0;r<16;r++) hur[r]=hu_in[(size_t)(m0+r)*64+l];
  #pragma unroll
  for(int r=0;r<16;r++){
    float a0=zx[(size_t)(m0+r)*256+g],a1=0.f;
    #pragma unroll
    for(int k=0;k<64;k+=2){
      float h0=rdl(hur[r],k), h1=rdl(hur[r],k+1);
      a0=fmaf(wr[k]  ,h0,a0);
      a1=fmaf(wr[k+1],h1,a1);
    }
    sbuf[r*256+tid]=a0+a1;
  }
  __syncthreads();
  #pragma unroll
  for(int q=0;q<4;q++){
    int r=q*4+w; size_t m=(size_t)(m0+r);
    float zi=sbuf[r*256+l], zf=sbuf[r*256+64+l], zg=sbuf[r*256+128+l], zo=sbuf[r*256+192+l];
    float c=sigm_f(zf)*c_in[m*64+l]+sigm_f(zi)*tanh_f(zg);
    sbuf[4096 + r*64 + l]=sigm_f(zo)*tanh_f(c)+x[m*64+l];   // h_fin
  }
  __syncthreads();
  float hreg[16], tnorm[16];
  #pragma unroll
  for(int r=0;r<16;r++) hreg[r]=sbuf[4096+r*64+l];
  #pragma unroll
  for(int t=0;t<16;t++){
    float s=hreg[t]*hreg[t];
    #pragma unroll
    for(int o=32;o>0;o>>=1) s+=__shfl_xor(s,o,64);
    tnorm[t]=sqrtf(s);
  }
  bool valid=g<NKn;
  float snj = valid ? sn[(size_t)b*NKn+g] : 1.f;
  float s4f[64];
  if(valid){
    const float4* sp=(const float4*)(semb+((size_t)b*NKn+g)*64);
    #pragma unroll
    for(int q=0;q<16;q++){ float4 v=sp[q]; s4f[4*q]=v.x; s4f[4*q+1]=v.y; s4f[4*q+2]=v.z; s4f[4*q+3]=v.w; }
  } else {
    #pragma unroll
    for(int q=0;q<64;q++) s4f[q]=0.f;
  }
  float scr[16];
  #pragma unroll
  for(int t=0;t<16;t++){
    float a0=0.f,a1=0.f;
    #pragma unroll
    for(int k=0;k<64;k+=2){
      float h0=rdl(hreg[t],k), h1=rdl(hreg[t],k+1);
      a0=fmaf(s4f[k]  ,h0,a0);
      a1=fmaf(s4f[k+1],h1,a1);
    }
    scr[t]=(a0+a1) / fmaxf(tnorm[t]*snj,1e-8f);
  }
  float mx[16];
  #pragma unroll
  for(int t=0;t<16;t++){
    float m = valid ? scr[t] : -1e30f;
    #pragma unroll
    for(int o=32;o>0;o>>=1) m=fmaxf(m,__shfl_xor(m,o,64));
    mx[t]=m;
  }
  if(l==0){
    #pragma unroll
    for(int t=0;t<16;t++) wredA[t*4+w]=mx[t];
  }
  __syncthreads();
  float ex[16];
  #pragma unroll
  for(int t=0;t<16;t++){
    const float4 m4=*(const float4*)&wredA[t*4];
    float gm=fmaxf(fmaxf(m4.x,m4.y),fmaxf(m4.z,m4.w));
    float e=valid?__expf(scr[t]-gm):0.f;
    ex[t]=e;
    float s=e;
    #pragma unroll
    for(int o=32;o>0;o>>=1) s+=__shfl_xor(s,o,64);
    mx[t]=s;
  }
  if(l==0){
    #pragma unroll
    for(int t=0;t<16;t++) wredB[t*4+w]=mx[t];
  }
  __syncthreads();
  #pragma unroll
  for(int t=0;t<16;t++){
    const float4 s4v=*(const float4*)&wredB[t*4];
    float tot=(s4v.x+s4v.y)+(s4v.z+s4v.w);
    if(valid) out[((size_t)(m0+t))*NKn + g]=ex[t]*(1.0f/tot);
  }
}

extern "C" void kernel_launch(void* const* d_in, const int* in_sizes, int n_in,
                              void* d_out, int out_size, void* d_ws, size_t ws_size,
                              hipStream_t stream) {
  (void)in_sizes; (void)n_in; (void)out_size; (void)ws_size;
  const int*   sup_toks = (const int*)d_in[0];
  const int*   tgt_toks = (const int*)d_in[1];
  const float* emb      = (const float*)d_in[2];
  const float* f_Wih    = (const float*)d_in[3];
  const float* f_Whh    = (const float*)d_in[4];
  const float* f_bih    = (const float*)d_in[5];
  const float* f_bhh    = (const float*)d_in[6];
  const float* gf_Wih   = (const float*)d_in[7];
  const float* gf_Whh   = (const float*)d_in[8];
  const float* gf_bih   = (const float*)d_in[9];
  const float* gf_bhh   = (const float*)d_in[10];
  const float* gb_Wih   = (const float*)d_in[11];
  const float* gb_Whh   = (const float*)d_in[12];
  const float* gb_bih   = (const float*)d_in[13];
  const float* gb_bhh   = (const float*)d_in[14];

  float* ws = (float*)d_ws;
  float* sup_enc = ws;                         // 819200
  float* tgt_enc = sup_enc + 819200;           // 524288
  float* bufA    = tgt_enc + 524288;           // 3276800 : xg_f, later zx
  float* bufB    = bufA    + 3276800;          // 3276800 : xg_b, later huA/huB/c
  float* semb    = bufB    + 3276800;          // 819200  : hf, then sup_emb
  float* hb      = semb    + 819200;           // 819200
  float* sn      = hb      + 819200;           // 12800

  float* xg_f = bufA;
  float* xg_b = bufB;

  embed_all<<<1312,256,0,stream>>>(sup_toks, tgt_toks, emb, sup_enc, tgt_enc);
  gemm_sup<<<1600,256,0,stream>>>(sup_enc, gf_Wih, gb_Wih,
                                  gf_bih, gf_bhh, gb_bih, gb_bhh, xg_f, xg_b);
  lstm_seq2<<<64,256,0,stream>>>(xg_f, xg_b, gf_Whh, gb_Whh, semb /*hf*/, hb);

  float* zx   = bufA;                  // xg_f dead after lstm
  float* huA  = bufB;                  // xg_b dead after lstm
  float* huB  = huA + 524288;
  float* cbuf = huB + 524288;

  gemmz_combine<<<1312,256,0,stream>>>(tgt_enc, f_Wih, f_bih, f_bhh, zx,
                                       semb, hb, sup_enc, semb, sn);

  // K=5: hu ping-pong; k=0 zero-init; k=4 fused with final softmax
  fused_cell_attn<<<512,256,0,stream>>>(huA, zx, f_Whh, tgt_enc, cbuf, semb, huA, 1);
  fused_cell_attn<<<512,256,0,stream>>>(huA, zx, f_Whh, tgt_enc, cbuf, semb, huB, 0);
  fused_cell_attn<<<512,256,0,stream>>>(huB, zx, f_Whh, tgt_enc, cbuf, semb, huA, 0);
  fused_cell_attn<<<512,256,0,stream>>>(huA, zx, f_Whh, tgt_enc, cbuf, semb, huB, 0);
  fused_cell_final<<<512,256,0,stream>>>(huB, zx, f_Whh, tgt_enc, cbuf, semb, sn, (float*)d_out);
}

// Round 6
// 446.895 us; speedup vs baseline: 1.2022x; 1.1383x over previous
//
#include <hip/hip_runtime.h>

#define Bn   64
#define Tn   128
#define NKn  200
#define En   64
#define Ln   40

__device__ __forceinline__ float sigm_f(float x){ return 1.0f/(1.0f+__expf(-x)); }
__device__ __forceinline__ float tanh_f(float x){ float e=__expf(2.0f*x); return 1.0f-2.0f/(e+1.0f); }

// ---------------- both embedding gather-sums in one grid ----------------
__global__ __launch_bounds__(256) void embed_all(const int* __restrict__ sup,
                                                 const int* __restrict__ tgt,
                                                 const float* __restrict__ emb,
                                                 float* __restrict__ sup_enc,
                                                 float* __restrict__ tgt_enc){
  int tid = threadIdx.x;
  int gr  = blockIdx.x*16 + (tid>>4);
  int e4  = tid & 15;
  const int* tr; float* out;
  if (gr < 12800){ tr = sup + (size_t)gr*Ln;        out = sup_enc + (size_t)gr*64; }
  else           { int r2=gr-12800; tr = tgt + (size_t)r2*Ln; out = tgt_enc + (size_t)r2*64; }
  float4 acc = {0.f,0.f,0.f,0.f};
  #pragma unroll 4
  for (int t=0;t<Ln;t++){
    int tok = tr[t];
    float4 v = ((const float4*)emb)[(size_t)tok*16 + e4];
    acc.x+=v.x; acc.y+=v.y; acc.z+=v.z; acc.w+=v.w;
  }
  ((float4*)out)[e4] = acc;
}

// ---------------- both support GEMMs: x tile staged in LDS, wave-uniform b128 broadcast ----
__global__ __launch_bounds__(256,2) void gemm_sup(const float* __restrict__ x,
                                                  const float* __restrict__ Wa, const float* __restrict__ Wb,
                                                  const float* __restrict__ ba1,const float* __restrict__ ba2,
                                                  const float* __restrict__ bb1,const float* __restrict__ bb2,
                                                  float* __restrict__ outa, float* __restrict__ outb){
  int tid=threadIdx.x, l=tid&63, w=tid>>6;
  int g=tid;
  int blk = blockIdx.x;
  bool second = blk>=800;
  const float* W  = second? Wb : Wa;
  const float* b1 = second? bb1: ba1;
  const float* b2 = second? bb2: ba2;
  float* out      = second? outb: outa;
  int m0 = (second? blk-800 : blk)*16;
  __shared__ __attribute__((aligned(16))) float xs[16*64];
  #pragma unroll
  for(int q=0;q<4;q++){ int r=4*w+q; xs[r*64+l]=x[(size_t)(m0+r)*64+l]; }
  float wr[64];
  const float4* W4=(const float4*)(W + (size_t)g*64);
  #pragma unroll
  for(int q=0;q<16;q++){ float4 v=W4[q]; wr[4*q]=v.x; wr[4*q+1]=v.y; wr[4*q+2]=v.z; wr[4*q+3]=v.w; }
  float bias=b1[g]+b2[g];
  __syncthreads();
  #pragma unroll
  for(int r=0;r<16;r++){
    const float4* x4=(const float4*)&xs[r*64];
    float a0=bias,a1=0.f,a2=0.f,a3=0.f;
    #pragma unroll
    for(int kc=0;kc<16;kc++){
      float4 h4=x4[kc];                      // wave-uniform -> LDS broadcast, no hazard
      a0=fmaf(wr[4*kc+0],h4.x,a0);
      a1=fmaf(wr[4*kc+1],h4.y,a1);
      a2=fmaf(wr[4*kc+2],h4.z,a2);
      a3=fmaf(wr[4*kc+3],h4.w,a3);
    }
    out[(size_t)(m0+r)*256+g]=(a0+a1)+(a2+a3);
  }
}

// ---------------- BiLSTM: hazard-free GEMV via per-wave replicated h in LDS --------------
// 128 blocks x 256 thr, thread = gate g. Each wave keeps its own copy of h in h_s[w][64]
// (write + 16 b128 broadcast reads are in-wave ordered -> no second barrier). One
// parity-buffered barrier per step for z. Activations replicated in all 4 waves.
__global__ __launch_bounds__(256,1) void lstm_rep(const float* __restrict__ xg_f,
                                                  const float* __restrict__ xg_b,
                                                  const float* __restrict__ Whh_f,
                                                  const float* __restrict__ Whh_b,
                                                  float* __restrict__ hf,
                                                  float* __restrict__ hb){
  int tid=threadIdx.x, l=tid&63, w=tid>>6;
  int dir=blockIdx.x>>6, b=blockIdx.x&63;
  const float* xg = dir? xg_b : xg_f;
  const float* Whh= dir? Whh_b: Whh_f;
  float* out      = dir? hb : hf;
  int g=tid;
  float wr[64];
  {
    const float4* W4=(const float4*)(Whh+(size_t)g*64);
    #pragma unroll
    for(int q=0;q<16;q++){ float4 v=W4[q]; wr[4*q]=v.x; wr[4*q+1]=v.y; wr[4*q+2]=v.z; wr[4*q+3]=v.w; }
  }
  __shared__ float z_s[2][256];
  __shared__ __attribute__((aligned(16))) float h_s[4][64];
  h_s[w][l]=0.f;                       // own-wave buffer: no barrier needed
  float c=0.f;
  const int tstart = dir?(NKn-1):0, dt = dir?-1:1;
  const float* xgb = xg + (size_t)b*NKn*256 + g;
  float xp0 = xgb[(size_t)tstart*256];
  float xp1 = xgb[(size_t)(tstart+dt)*256];
  const float4* hs4=(const float4*)&h_s[w][0];
  for(int s=0;s<NKn;s++){
    int t=tstart+s*dt;
    float xnx=0.f;
    if (s+2<NKn) xnx = xgb[(size_t)(t+2*dt)*256];   // depth-2 prefetch
    float a0=0.f,a1=0.f,a2=0.f,a3=0.f;
    #pragma unroll
    for(int kc=0;kc<16;kc++){
      float4 h4=hs4[kc];                 // wave-uniform broadcast from own buffer
      a0=fmaf(wr[4*kc+0],h4.x,a0);
      a1=fmaf(wr[4*kc+1],h4.y,a1);
      a2=fmaf(wr[4*kc+2],h4.z,a2);
      a3=fmaf(wr[4*kc+3],h4.w,a3);
    }
    int p=s&1;
    z_s[p][g]=((a0+a1)+(a2+a3))+xp0;
    __syncthreads();
    float zi=z_s[p][l], zf=z_s[p][64+l], zg2=z_s[p][128+l], zo=z_s[p][192+l];
    c = sigm_f(zf)*c + sigm_f(zi)*tanh_f(zg2);      // replicated in all 4 waves
    float hval = sigm_f(zo)*tanh_f(c);
    h_s[w][l]=hval;                      // in-wave RAW with next step's broadcast reads
    if(w==0) out[((size_t)b*NKn+t)*64+l]=hval;
    xp0=xp1; xp1=xnx;
  }
}

// ---------------- zx GEMM (blocks 0..511) + combine/norms (blocks 512..1311) --------------
__global__ __launch_bounds__(256,2) void gemmz_combine(const float* __restrict__ tgt_enc,
                                                       const float* __restrict__ W,
                                                       const float* __restrict__ b1,
                                                       const float* __restrict__ b2,
                                                       float* __restrict__ zx,
                                                       const float* __restrict__ hf,
                                                       const float* __restrict__ hb,
                                                       const float* __restrict__ sup_enc,
                                                       float* __restrict__ semb,
                                                       float* __restrict__ sn){
  int tid=threadIdx.x, l=tid&63, w=tid>>6;
  int blk=blockIdx.x;
  if (blk < 512){
    int g=tid, m0=blk*16;
    __shared__ __attribute__((aligned(16))) float xs[16*64];
    #pragma unroll
    for(int q=0;q<4;q++){ int r=4*w+q; xs[r*64+l]=tgt_enc[(size_t)(m0+r)*64+l]; }
    float wr[64];
    const float4* W4=(const float4*)(W + (size_t)g*64);
    #pragma unroll
    for(int q=0;q<16;q++){ float4 v=W4[q]; wr[4*q]=v.x; wr[4*q+1]=v.y; wr[4*q+2]=v.z; wr[4*q+3]=v.w; }
    float bias=b1[g]+b2[g];
    __syncthreads();
    #pragma unroll
    for(int r=0;r<16;r++){
      const float4* x4=(const float4*)&xs[r*64];
      float a0=bias,a1=0.f,a2=0.f,a3=0.f;
      #pragma unroll
      for(int kc=0;kc<16;kc++){
        float4 h4=x4[kc];
        a0=fmaf(wr[4*kc+0],h4.x,a0);
        a1=fmaf(wr[4*kc+1],h4.y,a1);
        a2=fmaf(wr[4*kc+2],h4.z,a2);
        a3=fmaf(wr[4*kc+3],h4.w,a3);
      }
      zx[(size_t)(m0+r)*256+g]=(a0+a1)+(a2+a3);
    }
  } else {
    int m0=(blk-512)*16;
    #pragma unroll
    for(int q=0;q<4;q++){
      size_t m=(size_t)m0 + w*4 + q;
      float v = hf[m*64+l] + hb[m*64+l] + sup_enc[m*64+l];
      semb[m*64+l]=v;
      float s=v*v;
      #pragma unroll
      for (int o=32;o>0;o>>=1) s += __shfl_xor(s,o,64);
      if (l==0) sn[m]=sqrtf(s);
    }
  }
}

// ---------------- fused LSTM-cell + attention, hazard-free broadcasts ----------------
__global__ __launch_bounds__(256,2) void fused_cell_attn(const float* __restrict__ hu_in,
                                                         const float* __restrict__ zx,
                                                         const float* __restrict__ Whh,
                                                         const float* __restrict__ x,
                                                         float* __restrict__ c_io,
                                                         const float* __restrict__ semb,
                                                         float* __restrict__ hu_out,
                                                         int zero){
  int tid=threadIdx.x, l=tid&63, w=tid>>6;
  int b=blockIdx.x>>3, t0=(blockIdx.x&7)*16;
  int m0=b*Tn+t0;
  int g=tid;                      // gate index AND support-row index j
  __shared__ __attribute__((aligned(16))) float hu_s[16*64];   // 4 KB
  __shared__ __attribute__((aligned(16))) float sbuf[16*256];  // z 16 KB, reused as att[200*20]
  __shared__ __attribute__((aligned(16))) float hn_s[16*64];   // h_next, 4 KB
  __shared__ float wredA[64], wredB[64];
  bool valid = g<NKn;
  const float* sbase = semb + (size_t)b*NKn*64;
  // stage hu tile
  #pragma unroll
  for(int q=0;q<4;q++){ int r=4*w+q; hu_s[r*64+l] = zero? 0.f : hu_in[(size_t)(m0+r)*64+l]; }
  float wr[64];
  {
    const float4* W4=(const float4*)(Whh+(size_t)g*64);
    #pragma unroll
    for(int q=0;q<16;q++){ float4 v=W4[q]; wr[4*q]=v.x; wr[4*q+1]=v.y; wr[4*q+2]=v.z; wr[4*q+3]=v.w; }
  }
  float s4f[64];
  if(valid){
    const float4* sp=(const float4*)(sbase+(size_t)g*64);
    #pragma unroll
    for(int q=0;q<16;q++){ float4 v=sp[q]; s4f[4*q]=v.x; s4f[4*q+1]=v.y; s4f[4*q+2]=v.z; s4f[4*q+3]=v.w; }
  } else {
    #pragma unroll
    for(int q=0;q<64;q++) s4f[q]=0.f;
  }
  __syncthreads();
  // ---- fused cell + scores GEMV: shared wave-uniform b128 broadcast stream ----
  float scr[16];
  #pragma unroll
  for(int r=0;r<16;r++){
    float z0=zx[(size_t)(m0+r)*256+g], z1=0.f, sc0=0.f, sc1=0.f;
    if(!zero){
      const float4* h4p=(const float4*)&hu_s[r*64];
      #pragma unroll
      for(int kc=0;kc<16;kc++){
        float4 h4=h4p[kc];
        z0 =fmaf(wr[4*kc+0] ,h4.x,z0 ); sc0=fmaf(s4f[4*kc+0],h4.x,sc0);
        z1 =fmaf(wr[4*kc+1] ,h4.y,z1 ); sc1=fmaf(s4f[4*kc+1],h4.y,sc1);
        z0 =fmaf(wr[4*kc+2] ,h4.z,z0 ); sc0=fmaf(s4f[4*kc+2],h4.z,sc0);
        z1 =fmaf(wr[4*kc+3] ,h4.w,z1 ); sc1=fmaf(s4f[4*kc+3],h4.w,sc1);
      }
    }
    sbuf[r*256+g]=z0+z1;
    scr[r]=sc0+sc1;
  }
  __syncthreads();
  // ---- gates -> h_next (hn_s) ----
  #pragma unroll
  for(int q=0;q<4;q++){
    int r=q*4+w; size_t m=(size_t)(m0+r);
    float zi=sbuf[r*256+l], zf=sbuf[r*256+64+l], zg=sbuf[r*256+128+l], zo=sbuf[r*256+192+l];
    float cp = zero? 0.f : c_io[m*64+l];
    float c=sigm_f(zf)*cp+sigm_f(zi)*tanh_f(zg);
    c_io[m*64+l]=c;
    hn_s[r*64+l]=sigm_f(zo)*tanh_f(c)+x[m*64+l];
  }
  // ---- softmax over j for each of 16 targets ----
  float mx[16];
  #pragma unroll
  for(int t=0;t<16;t++){
    float m = valid ? scr[t] : -1e30f;
    #pragma unroll
    for(int o=32;o>0;o>>=1) m=fmaxf(m,__shfl_xor(m,o,64));
    mx[t]=m;
  }
  if(l==0){
    #pragma unroll
    for(int t=0;t<16;t++) wredA[t*4+w]=mx[t];
  }
  __syncthreads();                   // z/hn writes+reads settled before att overwrites sbuf
  float ex[16];
  #pragma unroll
  for(int t=0;t<16;t++){
    const float4 m4=*(const float4*)&wredA[t*4];
    float gm=fmaxf(fmaxf(m4.x,m4.y),fmaxf(m4.z,m4.w));
    float e=valid?__expf(scr[t]-gm):0.f;
    ex[t]=e;
    float s=e;
    #pragma unroll
    for(int o=32;o>0;o>>=1) s+=__shfl_xor(s,o,64);
    mx[t]=s;
  }
  if(l==0){
    #pragma unroll
    for(int t=0;t<16;t++) wredB[t*4+w]=mx[t];
  }
  __syncthreads();
  #pragma unroll
  for(int t=0;t<16;t++){
    const float4 s4v=*(const float4*)&wredB[t*4];
    float tot=(s4v.x+s4v.y)+(s4v.z+s4v.w);
    ex[t]*=1.0f/tot;                 // att
  }
  if(valid){
    #pragma unroll
    for(int cg=0;cg<4;cg++)
      *(float4*)&sbuf[g*20+4*cg]=make_float4(ex[4*cg+0],ex[4*cg+1],ex[4*cg+2],ex[4*cg+3]);
  }
  __syncthreads();
  // ---- r-phase: att via wave-uniform b128 broadcast (stride 20 fl = 80 B, 16B-aligned) ----
  float r0=0.f,r1=0.f,r2=0.f,r3=0.f;
  #pragma unroll 8
  for(int j=0;j<NKn;j++){
    float4 a4=*(const float4*)&sbuf[j*20+w*4];
    float sv=sbase[(size_t)j*64+l];          // L2-resident, coalesced
    r0=fmaf(a4.x,sv,r0);
    r1=fmaf(a4.y,sv,r1);
    r2=fmaf(a4.z,sv,r2);
    r3=fmaf(a4.w,sv,r3);
  }
  {
    int rb=w*4;
    size_t m=(size_t)(m0+rb);
    hu_out[(m+0)*64+l]=r0 + hn_s[(rb+0)*64+l];
    hu_out[(m+1)*64+l]=r1 + hn_s[(rb+1)*64+l];
    hu_out[(m+2)*64+l]=r2 + hn_s[(rb+2)*64+l];
    hu_out[(m+3)*64+l]=r3 + hn_s[(rb+3)*64+l];
  }
}

// ---------------- fused final cell + cosine-sim softmax -> d_out ----------------
__global__ __launch_bounds__(256,2) void fused_cell_final(const float* __restrict__ hu_in,
                                                          const float* __restrict__ zx,
                                                          const float* __restrict__ Whh,
                                                          const float* __restrict__ x,
                                                          const float* __restrict__ c_in,
                                                          const float* __restrict__ semb,
                                                          const float* __restrict__ sn,
                                                          float* __restrict__ out){
  int tid=threadIdx.x, l=tid&63, w=tid>>6;
  int b=blockIdx.x>>3, t0=(blockIdx.x&7)*16;
  int m0=b*Tn+t0;
  int g=tid;
  __shared__ __attribute__((aligned(16))) float hu_s[16*64];
  __shared__ __attribute__((aligned(16))) float sbuf[16*256];
  __shared__ __attribute__((aligned(16))) float hn_s[16*64];   // h_final
  __shared__ float wredA[64], wredB[64];
  bool valid=g<NKn;
  #pragma unroll
  for(int q=0;q<4;q++){ int r=4*w+q; hu_s[r*64+l]=hu_in[(size_t)(m0+r)*64+l]; }
  float wr[64];
  {
    const float4* W4=(const float4*)(Whh+(size_t)g*64);
    #pragma unroll
    for(int q=0;q<16;q++){ float4 v=W4[q]; wr[4*q]=v.x; wr[4*q+1]=v.y; wr[4*q+2]=v.z; wr[4*q+3]=v.w; }
  }
  __syncthreads();
  #pragma unroll
  for(int r=0;r<16;r++){
    const float4* h4p=(const float4*)&hu_s[r*64];
    float a0=zx[(size_t)(m0+r)*256+g],a1=0.f,a2=0.f,a3=0.f;
    #pragma unroll
    for(int kc=0;kc<16;kc++){
      float4 h4=h4p[kc];
      a0=fmaf(wr[4*kc+0],h4.x,a0);
      a1=fmaf(wr[4*kc+1],h4.y,a1);
      a2=fmaf(wr[4*kc+2],h4.z,a2);
      a3=fmaf(wr[4*kc+3],h4.w,a3);
    }
    sbuf[r*256+g]=(a0+a1)+(a2+a3);
  }
  __syncthreads();
  #pragma unroll
  for(int q=0;q<4;q++){
    int r=q*4+w; size_t m=(size_t)(m0+r);
    float zi=sbuf[r*256+l], zf=sbuf[r*256+64+l], zg=sbuf[r*256+128+l], zo=sbuf[r*256+192+l];
    float c=sigm_f(zf)*c_in[m*64+l]+sigm_f(zi)*tanh_f(zg);
    hn_s[r*64+l]=sigm_f(zo)*tanh_f(c)+x[m*64+l];   // h_fin
  }
  __syncthreads();
  float tnorm[16];
  #pragma unroll
  for(int t=0;t<16;t++){
    float v=hn_s[t*64+l];
    float s=v*v;
    #pragma unroll
    for(int o=32;o>0;o>>=1) s+=__shfl_xor(s,o,64);
    tnorm[t]=sqrtf(s);
  }
  float snj = valid ? sn[(size_t)b*NKn+g] : 1.f;
  float s4f[64];
  if(valid){
    const float4* sp=(const float4*)(semb+((size_t)b*NKn+g)*64);
    #pragma unroll
    for(int q=0;q<16;q++){ float4 v=sp[q]; s4f[4*q]=v.x; s4f[4*q+1]=v.y; s4f[4*q+2]=v.z; s4f[4*q+3]=v.w; }
  } else {
    #pragma unroll
    for(int q=0;q<64;q++) s4f[q]=0.f;
  }
  float scr[16];
  #pragma unroll
  for(int t=0;t<16;t++){
    const float4* h4p=(const float4*)&hn_s[t*64];
    float a0=0.f,a1=0.f;
    #pragma unroll
    for(int kc=0;kc<16;kc++){
      float4 h4=h4p[kc];
      a0=fmaf(s4f[4*kc+0],h4.x,a0);
      a1=fmaf(s4f[4*kc+1],h4.y,a1);
      a0=fmaf(s4f[4*kc+2],h4.z,a0);
      a1=fmaf(s4f[4*kc+3],h4.w,a1);
    }
    scr[t]=(a0+a1) / fmaxf(tnorm[t]*snj,1e-8f);
  }
  float mx[16];
  #pragma unroll
  for(int t=0;t<16;t++){
    float m = valid ? scr[t] : -1e30f;
    #pragma unroll
    for(int o=32;o>0;o>>=1) m=fmaxf(m,__shfl_xor(m,o,64));
    mx[t]=m;
  }
  if(l==0){
    #pragma unroll
    for(int t=0;t<16;t++) wredA[t*4+w]=mx[t];
  }
  __syncthreads();
  float ex[16];
  #pragma unroll
  for(int t=0;t<16;t++){
    const float4 m4=*(const float4*)&wredA[t*4];
    float gm=fmaxf(fmaxf(m4.x,m4.y),fmaxf(m4.z,m4.w));
    float e=valid?__expf(scr[t]-gm):0.f;
    ex[t]=e;
    float s=e;
    #pragma unroll
    for(int o=32;o>0;o>>=1) s+=__shfl_xor(s,o,64);
    mx[t]=s;
  }
  if(l==0){
    #pragma unroll
    for(int t=0;t<16;t++) wredB[t*4+w]=mx[t];
  }
  __syncthreads();
  #pragma unroll
  for(int t=0;t<16;t++){
    const float4 s4v=*(const float4*)&wredB[t*4];
    float tot=(s4v.x+s4v.y)+(s4v.z+s4v.w);
    if(valid) out[((size_t)(m0+t))*NKn + g]=ex[t]*(1.0f/tot);
  }
}

extern "C" void kernel_launch(void* const* d_in, const int* in_sizes, int n_in,
                              void* d_out, int out_size, void* d_ws, size_t ws_size,
                              hipStream_t stream) {
  (void)in_sizes; (void)n_in; (void)out_size; (void)ws_size;
  const int*   sup_toks = (const int*)d_in[0];
  const int*   tgt_toks = (const int*)d_in[1];
  const float* emb      = (const float*)d_in[2];
  const float* f_Wih    = (const float*)d_in[3];
  const float* f_Whh    = (const float*)d_in[4];
  const float* f_bih    = (const float*)d_in[5];
  const float* f_bhh    = (const float*)d_in[6];
  const float* gf_Wih   = (const float*)d_in[7];
  const float* gf_Whh   = (const float*)d_in[8];
  const float* gf_bih   = (const float*)d_in[9];
  const float* gf_bhh   = (const float*)d_in[10];
  const float* gb_Wih   = (const float*)d_in[11];
  const float* gb_Whh   = (const float*)d_in[12];
  const float* gb_bih   = (const float*)d_in[13];
  const float* gb_bhh   = (const float*)d_in[14];

  float* ws = (float*)d_ws;
  float* sup_enc = ws;                         // 819200
  float* tgt_enc = sup_enc + 819200;           // 524288
  float* bufA    = tgt_enc + 524288;           // 3276800 : xg_f, later zx
  float* bufB    = bufA    + 3276800;          // 3276800 : xg_b, later huA/huB/c
  float* semb    = bufB    + 3276800;           // 819200  : hf, then sup_emb
  float* hb      = semb    + 819200;           // 819200
  float* sn      = hb      + 819200;           // 12800

  float* xg_f = bufA;
  float* xg_b = bufB;

  embed_all<<<1312,256,0,stream>>>(sup_toks, tgt_toks, emb, sup_enc, tgt_enc);
  gemm_sup<<<1600,256,0,stream>>>(sup_enc, gf_Wih, gb_Wih,
                                  gf_bih, gf_bhh, gb_bih, gb_bhh, xg_f, xg_b);
  lstm_rep<<<128,256,0,stream>>>(xg_f, xg_b, gf_Whh, gb_Whh, semb /*hf*/, hb);

  float* zx   = bufA;                  // xg_f dead after lstm
  float* huA  = bufB;                  // xg_b dead after lstm
  float* huB  = huA + 524288;
  float* cbuf = huB + 524288;

  gemmz_combine<<<1312,256,0,stream>>>(tgt_enc, f_Wih, f_bih, f_bhh, zx,
                                       semb, hb, sup_enc, semb, sn);

  // K=5: hu ping-pong; k=0 zero-init; k=4 fused with final softmax
  fused_cell_attn<<<512,256,0,stream>>>(huA, zx, f_Whh, tgt_enc, cbuf, semb, huA, 1);
  fused_cell_attn<<<512,256,0,stream>>>(huA, zx, f_Whh, tgt_enc, cbuf, semb, huB, 0);
  fused_cell_attn<<<512,256,0,stream>>>(huB, zx, f_Whh, tgt_enc, cbuf, semb, huA, 0);
  fused_cell_attn<<<512,256,0,stream>>>(huA, zx, f_Whh, tgt_enc, cbuf, semb, huB, 0);
  fused_cell_final<<<512,256,0,stream>>>(huB, zx, f_Whh, tgt_enc, cbuf, semb, sn, (float*)d_out);
}

// Round 7
// 444.242 us; speedup vs baseline: 1.2094x; 1.0060x over previous
//
#include <hip/hip_runtime.h>

#define Bn   64
#define Tn   128
#define NKn  200
#define En   64
#define Ln   40

__device__ __forceinline__ float sigm_f(float x){ return 1.0f/(1.0f+__expf(-x)); }
__device__ __forceinline__ float tanh_f(float x){ float e=__expf(2.0f*x); return 1.0f-2.0f/(e+1.0f); }
__device__ __forceinline__ float rdl(float v, int ln){
  return __uint_as_float(__builtin_amdgcn_readlane(__float_as_uint(v), (unsigned)ln));
}

// ---------------- both embedding gather-sums in one grid ----------------
__global__ __launch_bounds__(256) void embed_all(const int* __restrict__ sup,
                                                 const int* __restrict__ tgt,
                                                 const float* __restrict__ emb,
                                                 float* __restrict__ sup_enc,
                                                 float* __restrict__ tgt_enc){
  int tid = threadIdx.x;
  int gr  = blockIdx.x*16 + (tid>>4);
  int e4  = tid & 15;
  const int* tr; float* out;
  if (gr < 12800){ tr = sup + (size_t)gr*Ln;        out = sup_enc + (size_t)gr*64; }
  else           { int r2=gr-12800; tr = tgt + (size_t)r2*Ln; out = tgt_enc + (size_t)r2*64; }
  float4 acc = {0.f,0.f,0.f,0.f};
  #pragma unroll 4
  for (int t=0;t<Ln;t++){
    int tok = tr[t];
    float4 v = ((const float4*)emb)[(size_t)tok*16 + e4];
    acc.x+=v.x; acc.y+=v.y; acc.z+=v.z; acc.w+=v.w;
  }
  ((float4*)out)[e4] = acc;
}

// ---------------- both support GEMMs: x tile staged in LDS, wave-uniform b128 broadcast ----
__global__ __launch_bounds__(256,2) void gemm_sup(const float* __restrict__ x,
                                                  const float* __restrict__ Wa, const float* __restrict__ Wb,
                                                  const float* __restrict__ ba1,const float* __restrict__ ba2,
                                                  const float* __restrict__ bb1,const float* __restrict__ bb2,
                                                  float* __restrict__ outa, float* __restrict__ outb){
  int tid=threadIdx.x, l=tid&63, w=tid>>6;
  int g=tid;
  int blk = blockIdx.x;
  bool second = blk>=800;
  const float* W  = second? Wb : Wa;
  const float* b1 = second? bb1: ba1;
  const float* b2 = second? bb2: ba2;
  float* out      = second? outb: outa;
  int m0 = (second? blk-800 : blk)*16;
  __shared__ __attribute__((aligned(16))) float xs[16*64];
  #pragma unroll
  for(int q=0;q<4;q++){ int r=4*w+q; xs[r*64+l]=x[(size_t)(m0+r)*64+l]; }
  float wr[64];
  const float4* W4=(const float4*)(W + (size_t)g*64);
  #pragma unroll
  for(int q=0;q<16;q++){ float4 v=W4[q]; wr[4*q]=v.x; wr[4*q+1]=v.y; wr[4*q+2]=v.z; wr[4*q+3]=v.w; }
  float bias=b1[g]+b2[g];
  __syncthreads();
  #pragma unroll
  for(int r=0;r<16;r++){
    const float4* x4=(const float4*)&xs[r*64];
    float a0=bias,a1=0.f,a2=0.f,a3=0.f;
    #pragma unroll
    for(int kc=0;kc<16;kc++){
      float4 h4=x4[kc];                      // wave-uniform -> LDS broadcast, no hazard
      a0=fmaf(wr[4*kc+0],h4.x,a0);
      a1=fmaf(wr[4*kc+1],h4.y,a1);
      a2=fmaf(wr[4*kc+2],h4.z,a2);
      a3=fmaf(wr[4*kc+3],h4.w,a3);
    }
    out[(size_t)(m0+r)*256+g]=(a0+a1)+(a2+a3);
  }
}

// ---------------- BiLSTM: R2 architecture + 8-step batched xg prefetch & h stores --------
// 128 blocks x 256 thr, thread = gate g. rdl broadcast from register h (replicated
// activations in all 4 waves). Triple-buffered xg (xa=grp, xb=grp+1, xc<-grp+2 issued
// after an early barrier) so most __syncthreads drains find nothing outstanding.
__global__ __launch_bounds__(256,1) void lstm_b8(const float* __restrict__ xg_f,
                                                 const float* __restrict__ xg_b,
                                                 const float* __restrict__ Whh_f,
                                                 const float* __restrict__ Whh_b,
                                                 float* __restrict__ hf,
                                                 float* __restrict__ hb){
  int tid=threadIdx.x, l=tid&63, w=tid>>6;
  int dir=blockIdx.x>>6, b=blockIdx.x&63;
  const float* xg = dir? xg_b : xg_f;
  const float* Whh= dir? Whh_b: Whh_f;
  float* out      = dir? hb : hf;
  int g=tid;
  float wr[64];
  {
    const float4* W4=(const float4*)(Whh+(size_t)g*64);
    #pragma unroll
    for(int q=0;q<16;q++){ float4 v=W4[q]; wr[4*q]=v.x; wr[4*q+1]=v.y; wr[4*q+2]=v.z; wr[4*q+3]=v.w; }
  }
  __shared__ float z_s[2][256];
  float h=0.f, c=0.f;
  const int tstart = dir?(NKn-1):0, dt = dir?-1:1;
  const float* xgb = xg + (size_t)b*NKn*256 + g;
  float xa[8], xb_[8], xc[8], hst[8];
  #pragma unroll
  for(int j=0;j<8;j++) xa[j]  = xgb[(size_t)(tstart + j*dt)*256];       // grp 0
  #pragma unroll
  for(int j=0;j<8;j++) xb_[j] = xgb[(size_t)(tstart + (8+j)*dt)*256];   // grp 1
  for(int grp=0; grp<25; grp++){
    int s0 = grp*8;
    #pragma unroll
    for(int j=0;j<8;j++){
      int s = s0 + j;
      float a0=xa[j],a1=0.f,a2=0.f,a3=0.f;
      #pragma unroll
      for(int q=0;q<16;q++){
        a0=fmaf(wr[4*q+0],rdl(h,4*q+0),a0);
        a1=fmaf(wr[4*q+1],rdl(h,4*q+1),a1);
        a2=fmaf(wr[4*q+2],rdl(h,4*q+2),a2);
        a3=fmaf(wr[4*q+3],rdl(h,4*q+3),a3);
      }
      int p=s&1;
      z_s[p][g]=(a0+a1)+(a2+a3);
      __syncthreads();                       // parity buffer: safe vs next step's write
      if (j==1 && grp<23){                   // issue grp+2 loads; >=14 steps of slack
        #pragma unroll
        for(int jj=0;jj<8;jj++)
          xc[jj] = xgb[(size_t)(tstart + (s0+16+jj)*dt)*256];
      }
      float zi=z_s[p][l], zf=z_s[p][64+l], zg2=z_s[p][128+l], zo=z_s[p][192+l];
      c = sigm_f(zf)*c + sigm_f(zi)*tanh_f(zg2);   // replicated per wave; h stays in regs
      h = sigm_f(zo)*tanh_f(c);
      hst[j]=h;
    }
    if (w==0){                               // batched stores: one drain per 8 steps
      #pragma unroll
      for(int j=0;j<8;j++){
        int t = tstart + (s0+j)*dt;
        out[((size_t)b*NKn+t)*64+l]=hst[j];
      }
    }
    #pragma unroll
    for(int j=0;j<8;j++){ xa[j]=xb_[j]; xb_[j]=xc[j]; }
  }
}

// ---------------- zx GEMM (blocks 0..511) + combine/norms (blocks 512..1311) --------------
__global__ __launch_bounds__(256,2) void gemmz_combine(const float* __restrict__ tgt_enc,
                                                       const float* __restrict__ W,
                                                       const float* __restrict__ b1,
                                                       const float* __restrict__ b2,
                                                       float* __restrict__ zx,
                                                       const float* __restrict__ hf,
                                                       const float* __restrict__ hb,
                                                       const float* __restrict__ sup_enc,
                                                       float* __restrict__ semb,
                                                       float* __restrict__ sn){
  int tid=threadIdx.x, l=tid&63, w=tid>>6;
  int blk=blockIdx.x;
  if (blk < 512){
    int g=tid, m0=blk*16;
    __shared__ __attribute__((aligned(16))) float xs[16*64];
    #pragma unroll
    for(int q=0;q<4;q++){ int r=4*w+q; xs[r*64+l]=tgt_enc[(size_t)(m0+r)*64+l]; }
    float wr[64];
    const float4* W4=(const float4*)(W + (size_t)g*64);
    #pragma unroll
    for(int q=0;q<16;q++){ float4 v=W4[q]; wr[4*q]=v.x; wr[4*q+1]=v.y; wr[4*q+2]=v.z; wr[4*q+3]=v.w; }
    float bias=b1[g]+b2[g];
    __syncthreads();
    #pragma unroll
    for(int r=0;r<16;r++){
      const float4* x4=(const float4*)&xs[r*64];
      float a0=bias,a1=0.f,a2=0.f,a3=0.f;
      #pragma unroll
      for(int kc=0;kc<16;kc++){
        float4 h4=x4[kc];
        a0=fmaf(wr[4*kc+0],h4.x,a0);
        a1=fmaf(wr[4*kc+1],h4.y,a1);
        a2=fmaf(wr[4*kc+2],h4.z,a2);
        a3=fmaf(wr[4*kc+3],h4.w,a3);
      }
      zx[(size_t)(m0+r)*256+g]=(a0+a1)+(a2+a3);
    }
  } else {
    int m0=(blk-512)*16;
    #pragma unroll
    for(int q=0;q<4;q++){
      size_t m=(size_t)m0 + w*4 + q;
      float v = hf[m*64+l] + hb[m*64+l] + sup_enc[m*64+l];
      semb[m*64+l]=v;
      float s=v*v;
      #pragma unroll
      for (int o=32;o>0;o>>=1) s += __shfl_xor(s,o,64);
      if (l==0) sn[m]=sqrtf(s);
    }
  }
}

// ---------------- fused LSTM-cell + attention, hazard-free broadcasts ----------------
__global__ __launch_bounds__(256,2) void fused_cell_attn(const float* __restrict__ hu_in,
                                                         const float* __restrict__ zx,
                                                         const float* __restrict__ Whh,
                                                         const float* __restrict__ x,
                                                         float* __restrict__ c_io,
                                                         const float* __restrict__ semb,
                                                         float* __restrict__ hu_out,
                                                         int zero){
  int tid=threadIdx.x, l=tid&63, w=tid>>6;
  int b=blockIdx.x>>3, t0=(blockIdx.x&7)*16;
  int m0=b*Tn+t0;
  int g=tid;                      // gate index AND support-row index j
  __shared__ __attribute__((aligned(16))) float hu_s[16*64];   // 4 KB
  __shared__ __attribute__((aligned(16))) float sbuf[16*256];  // z 16 KB, reused as att[200*20]
  __shared__ __attribute__((aligned(16))) float hn_s[16*64];   // h_next, 4 KB
  __shared__ float wredA[64], wredB[64];
  bool valid = g<NKn;
  const float* sbase = semb + (size_t)b*NKn*64;
  // stage hu tile
  #pragma unroll
  for(int q=0;q<4;q++){ int r=4*w+q; hu_s[r*64+l] = zero? 0.f : hu_in[(size_t)(m0+r)*64+l]; }
  float wr[64];
  {
    const float4* W4=(const float4*)(Whh+(size_t)g*64);
    #pragma unroll
    for(int q=0;q<16;q++){ float4 v=W4[q]; wr[4*q]=v.x; wr[4*q+1]=v.y; wr[4*q+2]=v.z; wr[4*q+3]=v.w; }
  }
  float s4f[64];
  if(valid){
    const float4* sp=(const float4*)(sbase+(size_t)g*64);
    #pragma unroll
    for(int q=0;q<16;q++){ float4 v=sp[q]; s4f[4*q]=v.x; s4f[4*q+1]=v.y; s4f[4*q+2]=v.z; s4f[4*q+3]=v.w; }
  } else {
    #pragma unroll
    for(int q=0;q<64;q++) s4f[q]=0.f;
  }
  __syncthreads();
  // ---- fused cell + scores GEMV: shared wave-uniform b128 broadcast stream ----
  float scr[16];
  #pragma unroll
  for(int r=0;r<16;r++){
    float z0=zx[(size_t)(m0+r)*256+g], z1=0.f, sc0=0.f, sc1=0.f;
    if(!zero){
      const float4* h4p=(const float4*)&hu_s[r*64];
      #pragma unroll
      for(int kc=0;kc<16;kc++){
        float4 h4=h4p[kc];
        z0 =fmaf(wr[4*kc+0] ,h4.x,z0 ); sc0=fmaf(s4f[4*kc+0],h4.x,sc0);
        z1 =fmaf(wr[4*kc+1] ,h4.y,z1 ); sc1=fmaf(s4f[4*kc+1],h4.y,sc1);
        z0 =fmaf(wr[4*kc+2] ,h4.z,z0 ); sc0=fmaf(s4f[4*kc+2],h4.z,sc0);
        z1 =fmaf(wr[4*kc+3] ,h4.w,z1 ); sc1=fmaf(s4f[4*kc+3],h4.w,sc1);
      }
    }
    sbuf[r*256+g]=z0+z1;
    scr[r]=sc0+sc1;
  }
  __syncthreads();
  // ---- gates -> h_next (hn_s) ----
  #pragma unroll
  for(int q=0;q<4;q++){
    int r=q*4+w; size_t m=(size_t)(m0+r);
    float zi=sbuf[r*256+l], zf=sbuf[r*256+64+l], zg=sbuf[r*256+128+l], zo=sbuf[r*256+192+l];
    float cp = zero? 0.f : c_io[m*64+l];
    float c=sigm_f(zf)*cp+sigm_f(zi)*tanh_f(zg);
    c_io[m*64+l]=c;
    hn_s[r*64+l]=sigm_f(zo)*tanh_f(c)+x[m*64+l];
  }
  // ---- softmax over j for each of 16 targets ----
  float mx[16];
  #pragma unroll
  for(int t=0;t<16;t++){
    float m = valid ? scr[t] : -1e30f;
    #pragma unroll
    for(int o=32;o>0;o>>=1) m=fmaxf(m,__shfl_xor(m,o,64));
    mx[t]=m;
  }
  if(l==0){
    #pragma unroll
    for(int t=0;t<16;t++) wredA[t*4+w]=mx[t];
  }
  __syncthreads();                   // z/hn writes+reads settled before att overwrites sbuf
  float ex[16];
  #pragma unroll
  for(int t=0;t<16;t++){
    const float4 m4=*(const float4*)&wredA[t*4];
    float gm=fmaxf(fmaxf(m4.x,m4.y),fmaxf(m4.z,m4.w));
    float e=valid?__expf(scr[t]-gm):0.f;
    ex[t]=e;
    float s=e;
    #pragma unroll
    for(int o=32;o>0;o>>=1) s+=__shfl_xor(s,o,64);
    mx[t]=s;
  }
  if(l==0){
    #pragma unroll
    for(int t=0;t<16;t++) wredB[t*4+w]=mx[t];
  }
  __syncthreads();
  #pragma unroll
  for(int t=0;t<16;t++){
    const float4 s4v=*(const float4*)&wredB[t*4];
    float tot=(s4v.x+s4v.y)+(s4v.z+s4v.w);
    ex[t]*=1.0f/tot;                 // att
  }
  if(valid){
    #pragma unroll
    for(int cg=0;cg<4;cg++)
      *(float4*)&sbuf[g*20+4*cg]=make_float4(ex[4*cg+0],ex[4*cg+1],ex[4*cg+2],ex[4*cg+3]);
  }
  __syncthreads();
  // ---- r-phase: att via wave-uniform b128 broadcast (stride 20 fl = 80 B, 16B-aligned) ----
  float r0=0.f,r1=0.f,r2=0.f,r3=0.f;
  #pragma unroll 8
  for(int j=0;j<NKn;j++){
    float4 a4=*(const float4*)&sbuf[j*20+w*4];
    float sv=sbase[(size_t)j*64+l];          // L2-resident, coalesced
    r0=fmaf(a4.x,sv,r0);
    r1=fmaf(a4.y,sv,r1);
    r2=fmaf(a4.z,sv,r2);
    r3=fmaf(a4.w,sv,r3);
  }
  {
    int rb=w*4;
    size_t m=(size_t)(m0+rb);
    hu_out[(m+0)*64+l]=r0 + hn_s[(rb+0)*64+l];
    hu_out[(m+1)*64+l]=r1 + hn_s[(rb+1)*64+l];
    hu_out[(m+2)*64+l]=r2 + hn_s[(rb+2)*64+l];
    hu_out[(m+3)*64+l]=r3 + hn_s[(rb+3)*64+l];
  }
}

// ---------------- fused final cell + cosine-sim softmax -> d_out ----------------
__global__ __launch_bounds__(256,2) void fused_cell_final(const float* __restrict__ hu_in,
                                                          const float* __restrict__ zx,
                                                          const float* __restrict__ Whh,
                                                          const float* __restrict__ x,
                                                          const float* __restrict__ c_in,
                                                          const float* __restrict__ semb,
                                                          const float* __restrict__ sn,
                                                          float* __restrict__ out){
  int tid=threadIdx.x, l=tid&63, w=tid>>6;
  int b=blockIdx.x>>3, t0=(blockIdx.x&7)*16;
  int m0=b*Tn+t0;
  int g=tid;
  __shared__ __attribute__((aligned(16))) float hu_s[16*64];
  __shared__ __attribute__((aligned(16))) float sbuf[16*256];
  __shared__ __attribute__((aligned(16))) float hn_s[16*64];   // h_final
  __shared__ float wredA[64], wredB[64];
  bool valid=g<NKn;
  #pragma unroll
  for(int q=0;q<4;q++){ int r=4*w+q; hu_s[r*64+l]=hu_in[(size_t)(m0+r)*64+l]; }
  float wr[64];
  {
    const float4* W4=(const float4*)(Whh+(size_t)g*64);
    #pragma unroll
    for(int q=0;q<16;q++){ float4 v=W4[q]; wr[4*q]=v.x; wr[4*q+1]=v.y; wr[4*q+2]=v.z; wr[4*q+3]=v.w; }
  }
  __syncthreads();
  #pragma unroll
  for(int r=0;r<16;r++){
    const float4* h4p=(const float4*)&hu_s[r*64];
    float a0=zx[(size_t)(m0+r)*256+g],a1=0.f,a2=0.f,a3=0.f;
    #pragma unroll
    for(int kc=0;kc<16;kc++){
      float4 h4=h4p[kc];
      a0=fmaf(wr[4*kc+0],h4.x,a0);
      a1=fmaf(wr[4*kc+1],h4.y,a1);
      a2=fmaf(wr[4*kc+2],h4.z,a2);
      a3=fmaf(wr[4*kc+3],h4.w,a3);
    }
    sbuf[r*256+g]=(a0+a1)+(a2+a3);
  }
  __syncthreads();
  #pragma unroll
  for(int q=0;q<4;q++){
    int r=q*4+w; size_t m=(size_t)(m0+r);
    float zi=sbuf[r*256+l], zf=sbuf[r*256+64+l], zg=sbuf[r*256+128+l], zo=sbuf[r*256+192+l];
    float c=sigm_f(zf)*c_in[m*64+l]+sigm_f(zi)*tanh_f(zg);
    hn_s[r*64+l]=sigm_f(zo)*tanh_f(c)+x[m*64+l];   // h_fin
  }
  __syncthreads();
  float tnorm[16];
  #pragma unroll
  for(int t=0;t<16;t++){
    float v=hn_s[t*64+l];
    float s=v*v;
    #pragma unroll
    for(int o=32;o>0;o>>=1) s+=__shfl_xor(s,o,64);
    tnorm[t]=sqrtf(s);
  }
  float snj = valid ? sn[(size_t)b*NKn+g] : 1.f;
  float s4f[64];
  if(valid){
    const float4* sp=(const float4*)(semb+((size_t)b*NKn+g)*64);
    #pragma unroll
    for(int q=0;q<16;q++){ float4 v=sp[q]; s4f[4*q]=v.x; s4f[4*q+1]=v.y; s4f[4*q+2]=v.z; s4f[4*q+3]=v.w; }
  } else {
    #pragma unroll
    for(int q=0;q<64;q++) s4f[q]=0.f;
  }
  float scr[16];
  #pragma unroll
  for(int t=0;t<16;t++){
    const float4* h4p=(const float4*)&hn_s[t*64];
    float a0=0.f,a1=0.f;
    #pragma unroll
    for(int kc=0;kc<16;kc++){
      float4 h4=h4p[kc];
      a0=fmaf(s4f[4*kc+0],h4.x,a0);
      a1=fmaf(s4f[4*kc+1],h4.y,a1);
      a0=fmaf(s4f[4*kc+2],h4.z,a0);
      a1=fmaf(s4f[4*kc+3],h4.w,a1);
    }
    scr[t]=(a0+a1) / fmaxf(tnorm[t]*snj,1e-8f);
  }
  float mx[16];
  #pragma unroll
  for(int t=0;t<16;t++){
    float m = valid ? scr[t] : -1e30f;
    #pragma unroll
    for(int o=32;o>0;o>>=1) m=fmaxf(m,__shfl_xor(m,o,64));
    mx[t]=m;
  }
  if(l==0){
    #pragma unroll
    for(int t=0;t<16;t++) wredA[t*4+w]=mx[t];
  }
  __syncthreads();
  float ex[16];
  #pragma unroll
  for(int t=0;t<16;t++){
    const float4 m4=*(const float4*)&wredA[t*4];
    float gm=fmaxf(fmaxf(m4.x,m4.y),fmaxf(m4.z,m4.w));
    float e=valid?__expf(scr[t]-gm):0.f;
    ex[t]=e;
    float s=e;
    #pragma unroll
    for(int o=32;o>0;o>>=1) s+=__shfl_xor(s,o,64);
    mx[t]=s;
  }
  if(l==0){
    #pragma unroll
    for(int t=0;t<16;t++) wredB[t*4+w]=mx[t];
  }
  __syncthreads();
  #pragma unroll
  for(int t=0;t<16;t++){
    const float4 s4v=*(const float4*)&wredB[t*4];
    float tot=(s4v.x+s4v.y)+(s4v.z+s4v.w);
    if(valid) out[((size_t)(m0+t))*NKn + g]=ex[t]*(1.0f/tot);
  }
}

extern "C" void kernel_launch(void* const* d_in, const int* in_sizes, int n_in,
                              void* d_out, int out_size, void* d_ws, size_t ws_size,
                              hipStream_t stream) {
  (void)in_sizes; (void)n_in; (void)out_size; (void)ws_size;
  const int*   sup_toks = (const int*)d_in[0];
  const int*   tgt_toks = (const int*)d_in[1];
  const float* emb      = (const float*)d_in[2];
  const float* f_Wih    = (const float*)d_in[3];
  const float* f_Whh    = (const float*)d_in[4];
  const float* f_bih    = (const float*)d_in[5];
  const float* f_bhh    = (const float*)d_in[6];
  const float* gf_Wih   = (const float*)d_in[7];
  const float* gf_Whh   = (const float*)d_in[8];
  const float* gf_bih   = (const float*)d_in[9];
  const float* gf_bhh   = (const float*)d_in[10];
  const float* gb_Wih   = (const float*)d_in[11];
  const float* gb_Whh   = (const float*)d_in[12];
  const float* gb_bih   = (const float*)d_in[13];
  const float* gb_bhh   = (const float*)d_in[14];

  float* ws = (float*)d_ws;
  float* sup_enc = ws;                         // 819200
  float* tgt_enc = sup_enc + 819200;           // 524288
  float* bufA    = tgt_enc + 524288;           // 3276800 : xg_f, later zx
  float* bufB    = bufA    + 3276800;          // 3276800 : xg_b, later huA/huB/c
  float* semb    = bufB    + 3276800;          // 819200  : hf, then sup_emb
  float* hb      = semb    + 819200;           // 819200
  float* sn      = hb      + 819200;           // 12800

  float* xg_f = bufA;
  float* xg_b = bufB;

  embed_all<<<1312,256,0,stream>>>(sup_toks, tgt_toks, emb, sup_enc, tgt_enc);
  gemm_sup<<<1600,256,0,stream>>>(sup_enc, gf_Wih, gb_Wih,
                                  gf_bih, gf_bhh, gb_bih, gb_bhh, xg_f, xg_b);
  lstm_b8<<<128,256,0,stream>>>(xg_f, xg_b, gf_Whh, gb_Whh, semb /*hf*/, hb);

  float* zx   = bufA;                  // xg_f dead after lstm
  float* huA  = bufB;                  // xg_b dead after lstm
  float* huB  = huA + 524288;
  float* cbuf = huB + 524288;

  gemmz_combine<<<1312,256,0,stream>>>(tgt_enc, f_Wih, f_bih, f_bhh, zx,
                                       semb, hb, sup_enc, semb, sn);

  // K=5: hu ping-pong; k=0 zero-init; k=4 fused with final softmax
  fused_cell_attn<<<512,256,0,stream>>>(huA, zx, f_Whh, tgt_enc, cbuf, semb, huA, 1);
  fused_cell_attn<<<512,256,0,stream>>>(huA, zx, f_Whh, tgt_enc, cbuf, semb, huB, 0);
  fused_cell_attn<<<512,256,0,stream>>>(huB, zx, f_Whh, tgt_enc, cbuf, semb, huA, 0);
  fused_cell_attn<<<512,256,0,stream>>>(huA, zx, f_Whh, tgt_enc, cbuf, semb, huB, 0);
  fused_cell_final<<<512,256,0,stream>>>(huB, zx, f_Whh, tgt_enc, cbuf, semb, sn, (float*)d_out);
}